// Round 14
// baseline (95.134 us; speedup 1.0000x reference)
//
#include <hip/hip_runtime.h>
#include <hip/hip_bf16.h>
#include <math.h>

#define N 2048
#define NC 8

// ws layout:
//   [0, 64)                  : double acc[8]            (zeroed by k_prep block 0)
//   [64, 64+128K)            : float2 psort[8][2048]    {s/ln2, A/ln2} in SCORE-SORTED order
//   [64+128K, 64+192K)       : int    lohi[8][2048]     (lo | hi<<16, per ORIGINAL row)
//   [64+192K, +4)            : unsigned counter         (ticket for fused finalize)
//   [64+192K+64, +32K)       : u16    origj[8][2048]    (sorted pos -> original j)

#if __has_builtin(__builtin_amdgcn_exp2f)
__device__ __forceinline__ float fexp2(float x) { return __builtin_amdgcn_exp2f(x); }
#else
__device__ __forceinline__ float fexp2(float x) { return exp2f(x); }
#endif
#if __has_builtin(__builtin_amdgcn_logf)
__device__ __forceinline__ float flog2(float x) { return __builtin_amdgcn_logf(x); }
#else
__device__ __forceinline__ float flog2(float x) { return log2f(x); }
#endif

#define INV_LN2 1.4426950408889634f
#define LN2_D   0.6931471805599453
#define CLAMP2  (-144.26950408889634f)   /* -100/ln2 : clamp in log2 domain */

// ---------------- Kernel 1: A-sum + score-rank + counting-rank GT -------------
// BYTE-IDENTICAL to R11/R12/R13. asum half computes score-rank and scatters
// psort[rank]={s,A}/ln2, origj[rank]=j; sortgt half unchanged.
__global__ __launch_bounds__(256) void k_prep(const float* __restrict__ logits,
                                              const float* __restrict__ dur,
                                              const int* __restrict__ ev,
                                              float2* __restrict__ psort,
                                              unsigned short* __restrict__ origj,
                                              int* __restrict__ lohi,
                                              double* __restrict__ acc,
                                              unsigned* __restrict__ counter) {
    __shared__ __align__(16) float s[N];                   // 8 KB   (asum)
    __shared__ double part[256];                           // 2 KB   (asum)
    __shared__ int pri[256];                               // 1 KB   (asum rank)
    __shared__ __align__(16) unsigned long long keys[N];   // 16 KB  (sortgt)
    __shared__ int pr[256], pv[256];                       // 2 KB   (sortgt)

    int b = blockIdx.x;
    int tid = threadIdx.x;

    if (b == 0) {  // zero accumulators + ticket for k_bce (stream-ordered)
        if (tid < 8) acc[tid] = 0.0;
        else if (tid == 8) counter[0] = 0u;
    }

    if (b < 512) {
        // ---- A-sum + rank, 32 j's per block, 8 i-slices of 256 ----
        int col = b >> 6, chunk = b & 63;
        for (int k = 0; k < N / 256; ++k) {
            int i = tid + k * 256;
            s[i] = logits[i * NC + col];
        }
        __syncthreads();
        int jl = tid & 31, slice = tid >> 5;   // 32 j-lanes x 8 slices
        int j = chunk * 32 + jl;
        float sj = s[j];
        const float4* s4 = (const float4*)(s + slice * 256);
        int ib = slice * 256;
        double a0 = 0.0, a1 = 0.0, a2 = 0.0, a3 = 0.0;
        int rk = 0;
        #pragma unroll 2
        for (int i = 0; i < 64; ++i) {
            float4 q = s4[i];
            int i0 = ib + 4 * i;
            a0 += (double)fabsf(sj - q.x);
            a1 += (double)fabsf(sj - q.y);
            a2 += (double)fabsf(sj - q.z);
            a3 += (double)fabsf(sj - q.w);
            rk += ((int)(q.x < sj)) | (((int)(q.x == sj)) & (int)(i0 + 0 < j));
            rk += ((int)(q.y < sj)) | (((int)(q.y == sj)) & (int)(i0 + 1 < j));
            rk += ((int)(q.z < sj)) | (((int)(q.z == sj)) & (int)(i0 + 2 < j));
            rk += ((int)(q.w < sj)) | (((int)(q.w == sj)) & (int)(i0 + 3 < j));
        }
        part[tid] = (a0 + a1) + (a2 + a3);
        pri[tid] = rk;
        __syncthreads();
        if (tid < 32) {
            double v = ((part[tid]       + part[tid + 32])  + (part[tid + 64]  + part[tid + 96])) +
                       ((part[tid + 128] + part[tid + 160]) + (part[tid + 192] + part[tid + 224]));
            int r = ((pri[tid]       + pri[tid + 32])  + (pri[tid + 64]  + pri[tid + 96])) +
                    ((pri[tid + 128] + pri[tid + 160]) + (pri[tid + 192] + pri[tid + 224]));
            psort[col * N + r] = make_float2(sj * INV_LN2, (float)v * INV_LN2);
            origj[col * N + r] = (unsigned short)j;
        }
    } else {
        // ---- counting-rank GT windows (UNCHANGED, R10 b128 form) ----
        int b2 = b - 512;
        int col = b2 >> 6, chunk = b2 & 63;
        for (int k = 0; k < N / 256; ++k) {
            int i = tid + k * 256;
            unsigned int db = __float_as_uint(dur[i * NC + col]);  // dur in [0,1)
            int e = ev[i * NC + col];
            keys[i] = ((unsigned long long)db << 32) | (unsigned int)((i << 1) | e);
        }
        __syncthreads();
        int jl = tid & 31, slice = tid >> 5;
        int j = chunk * 32 + jl;
        unsigned long long kj = keys[j];
        const ulonglong2* k2 = (const ulonglong2*)(keys + slice * 256);
        int rank = 0, evlt = 0;
        #pragma unroll 2
        for (int i = 0; i < 128; ++i) {
            ulonglong2 kk = k2[i];
            int lt0 = (kk.x < kj) ? 1 : 0;
            rank += lt0;
            evlt += lt0 & (int)(kk.x & 1ull);
            int lt1 = (kk.y < kj) ? 1 : 0;
            rank += lt1;
            evlt += lt1 & (int)(kk.y & 1ull);
        }
        pr[tid] = rank;
        pv[tid] = evlt;
        __syncthreads();
        if (tid < 32) {
            int r = ((pr[tid]       + pr[tid + 32])  + (pr[tid + 64]  + pr[tid + 96])) +
                    ((pr[tid + 128] + pr[tid + 160]) + (pr[tid + 192] + pr[tid + 224]));
            int v = ((pv[tid]       + pv[tid + 32])  + (pv[tid + 64]  + pv[tid + 96])) +
                    ((pv[tid + 128] + pv[tid + 160]) + (pv[tid + 192] + pv[tid + 224]));
            int e = (int)(kj & 1ull);
            int hi = e ? (r + 1) : N;
            lohi[col * N + j] = v | (hi << 16);
        }
    }
}

// ---------------- Kernel 2: softmax+BCE, DIRECT-L2 (no LDS staging) -----------
// R14 DISCRIMINATING PROBE (one variable vs R13): remove LDS staging entirely;
// all three passes read psort/origj straight from global (L2-resident: 20KB/col
// shared by 64 blocks; access pattern byte-identical coalescing — 64 lanes x
// 16B consecutive). Removes 64 LDS instrs/wave + 20KB staging + one barrier.
// R12 (ILP) and R13 (VALU-work removal) were both NEUTRAL -> k_bce's ~28us
// stall is NOT issue-work; the untouched terms are the LDS pipe (shared per-CU
// by 16 waves; shfl butterflies also live there) and staging. This isolates
// them. VGPR-cliff risk (r10 history) accepted: counters will name it if hit.
// Arithmetic and summation order byte-identical to R13 -> absmax 0.0.
__global__ __launch_bounds__(512) void k_bce(const float2* __restrict__ psort,
                                             const unsigned short* __restrict__ origj,
                                             const int* __restrict__ lohi,
                                             double* __restrict__ acc,
                                             unsigned* __restrict__ counter,
                                             float* __restrict__ out) {
    int col = blockIdx.x >> 6;   // 0..7
    int rg  = blockIdx.x & 63;   // 0..63 (32 rows each)
    __shared__ double bsum[8];
    int tid = threadIdx.x;
    int wave = tid >> 6, lane = tid & 63;

    const float4* p4 = (const float4*)(psort + (size_t)col * N);
    const unsigned* g4 = (const unsigned*)(origj + (size_t)col * N);

    int row0 = (rg << 5) + (wave << 2);   // 4 rows per wave, 8 waves
    float sc0 = (float)(N - 1 - 2 * row0);

    int lh[4];
    #pragma unroll
    for (int c = 0; c < 4; ++c) lh[c] = lohi[col * N + row0 + c];

    // pass 1: max of row 0 (permutation-invariant)
    float m = -INFINITY;
    #pragma unroll
    for (int k = 0; k < 16; ++k) {
        float4 q = p4[lane + (k << 6)];
        float t0 = fmaf(sc0, q.x, -q.y);
        float t1 = fmaf(sc0, q.z, -q.w);
        m = fmaxf(m, fmaxf(t0, t1));
    }
    #pragma unroll
    for (int off = 32; off > 0; off >>= 1)
        m = fmaxf(m, __shfl_xor(m, off, 64));

    // pass 2: se_c = sum fexp2(x_c), direct per-c; TRANS-free skip test first
    float se0 = 0.0f, se1 = 0.0f, se2 = 0.0f, se3 = 0.0f;
    #pragma unroll
    for (int k = 0; k < 16; ++k) {
        float4 q = p4[lane + (k << 6)];
        float tsa = q.x + q.x;
        float xa0 = fmaf(sc0, q.x, -q.y) - m;
        float xa3 = fmaf(-3.0f, tsa, xa0);
        float tsb = q.z + q.z;
        float xb0 = fmaf(sc0, q.z, -q.w) - m;
        float xb3 = fmaf(-3.0f, tsb, xb0);
        float hi = fmaxf(fmaxf(xa0, xa3), fmaxf(xb0, xb3));
        if (__all(hi < -152.0f)) continue;   // all E == +0: no se contribution
        float xa1 = xa0 - tsa;
        float xa2 = fmaf(-2.0f, tsa, xa0);
        float xb1 = xb0 - tsb;
        float xb2 = fmaf(-2.0f, tsb, xb0);
        se0 += fexp2(xa0); se1 += fexp2(xa1); se2 += fexp2(xa2); se3 += fexp2(xa3);
        se0 += fexp2(xb0); se1 += fexp2(xb1); se2 += fexp2(xb2); se3 += fexp2(xb3);
    }
    #pragma unroll
    for (int off = 32; off > 0; off >>= 1) {
        se0 += __shfl_xor(se0, off, 64);
        se1 += __shfl_xor(se1, off, 64);
        se2 += __shfl_xor(se2, off, 64);
        se3 += __shfl_xor(se3, off, 64);
    }
    float se[4] = {se0, se1, se2, se3};

    float L2v[4], C2v[4], yv[4], w2c[4];
    unsigned lo[4], wl[4];
    double rbase = 0.0;
    #pragma unroll
    for (int c = 0; c < 4; ++c) {
        float L2 = flog2(se[c]);
        L2v[c] = L2;
        rbase -= 2048.0 * (double)L2;
        C2v[c] = CLAMP2 + L2;
        w2c[c] = C2v[c] - L2v[c];        // deep-tier window value (bitwise)
        lo[c] = (unsigned)(lh[c] & 0xffff);
        wl[c] = (unsigned)((lh[c] >> 16) & 0xffff) - lo[c];
        yv[c] = 1.0f / (float)wl[c];
    }
    float minL2 = fminf(fminf(L2v[0], L2v[1]), fminf(L2v[2], L2v[3]));
    float C2min = fminf(fminf(C2v[0], C2v[1]), fminf(C2v[2], C2v[3]));
    float tdeep = fminf(C2min, minL2 - 27.0f);
    float t2    = minL2 - 27.0f;

    // pass 3: deep -> integer window counts only; mid -> no TRANS; hot -> full
    float a1[4] = {0.0f, 0.0f, 0.0f, 0.0f};
    float a2[4] = {0.0f, 0.0f, 0.0f, 0.0f};
    int cntD[4] = {0, 0, 0, 0};
    int nL = 0;
    #pragma unroll
    for (int k = 0; k < 16; ++k) {
        float4 q = p4[lane + (k << 6)];
        unsigned ow = g4[lane + (k << 6)];
        int ja = (int)(ow & 0xffffu), jb = (int)(ow >> 16);
        float tsa = q.x + q.x;
        float xa0 = fmaf(sc0, q.x, -q.y) - m;
        float xa3 = fmaf(-3.0f, tsa, xa0);
        float tsb = q.z + q.z;
        float xb0 = fmaf(sc0, q.z, -q.w) - m;
        float xb3 = fmaf(-3.0f, tsb, xb0);
        float hi = fmaxf(fmaxf(xa0, xa3), fmaxf(xb0, xb3));
        if (__all(hi < tdeep)) {
            // mx1 == C2v[c] and mx2 == L2v[c] bitwise: only window COUNTS
            ++nL;
            #pragma unroll
            for (int c = 0; c < 4; ++c) {
                cntD[c] += (int)((unsigned)(ja - lo[c]) < wl[c]);
                cntD[c] += (int)((unsigned)(jb - lo[c]) < wl[c]);
            }
        } else if (__all(hi < t2)) {
            // mx2 == L2v[c] bitwise (se-E rounds to se); mx1 needs x
            ++nL;
            {
                float x = xa0;
                #pragma unroll
                for (int c = 0; c < 4; ++c) {
                    float mx1 = fmaxf(x, C2v[c]);
                    float w = ((unsigned)(ja - lo[c]) < wl[c]) ? (mx1 - L2v[c]) : 0.0f;
                    a2[c] += w;
                    x -= tsa;
                }
            }
            {
                float x = xb0;
                #pragma unroll
                for (int c = 0; c < 4; ++c) {
                    float mx1 = fmaxf(x, C2v[c]);
                    float w = ((unsigned)(jb - lo[c]) < wl[c]) ? (mx1 - L2v[c]) : 0.0f;
                    a2[c] += w;
                    x -= tsb;
                }
            }
        } else {
            // hot: full direct-E path (R12)
            float xav[4], xbv[4];
            xav[0] = xa0; xav[1] = xa0 - tsa;
            xav[2] = fmaf(-2.0f, tsa, xa0); xav[3] = xa3;
            xbv[0] = xb0; xbv[1] = xb0 - tsb;
            xbv[2] = fmaf(-2.0f, tsb, xb0); xbv[3] = xb3;
            float Ea[4], Eb[4];
            #pragma unroll
            for (int c = 0; c < 4; ++c) { Ea[c] = fexp2(xav[c]); Eb[c] = fexp2(xbv[c]); }
            #pragma unroll
            for (int c = 0; c < 4; ++c) {
                float mx2a = fmaxf(flog2(se[c] - Ea[c]), C2v[c]);
                a1[c] += mx2a;
                float mx1a = fmaxf(xav[c], C2v[c]);
                float wa = ((unsigned)(ja - lo[c]) < wl[c]) ? (mx1a - mx2a) : 0.0f;
                a2[c] += wa;
                float mx2b = fmaxf(flog2(se[c] - Eb[c]), C2v[c]);
                a1[c] += mx2b;
                float mx1b = fmaxf(xbv[c], C2v[c]);
                float wb = ((unsigned)(jb - lo[c]) < wl[c]) ? (mx1b - mx2b) : 0.0f;
                a2[c] += wb;
            }
        }
    }
    // closed-form folds: a1 from deep+mid iters; a2 from deep-tier counts
    float fnL2 = 2.0f * (float)nL;
    #pragma unroll
    for (int c = 0; c < 4; ++c) {
        a1[c] = fmaf(fnL2, L2v[c], a1[c]);
        a2[c] = fmaf((float)cntD[c], w2c[c], a2[c]);
    }
    float r = 0.0f;
    #pragma unroll
    for (int c = 0; c < 4; ++c) r += fmaf(yv[c], a2[c], a1[c]);
    #pragma unroll
    for (int off = 32; off > 0; off >>= 1)
        r += __shfl_xor(r, off, 64);

    if (lane == 0) bsum[wave] = rbase + (double)r;
    __syncthreads();
    if (tid == 0) {
        double tot = ((bsum[0] + bsum[1]) + (bsum[2] + bsum[3])) +
                     ((bsum[4] + bsum[5]) + (bsum[6] + bsum[7]));
        atomicAdd(&acc[col], LN2_D * tot);
        __threadfence();
        unsigned old = atomicAdd(counter, 1u);
        if (old == (unsigned)(NC * 64 - 1)) {  // last of 512 blocks
            __threadfence();
            float ssum = 0.0f;
            int cnt = 0;
            for (int c = 0; c < NC; ++c) {
                double av2 = atomicAdd(&acc[c], 0.0);  // device-scope read
                float lc = (float)(-av2 / ((double)N * (double)N));
                if (lc > 0.0f) { ssum += lc; cnt++; }
            }
            out[0] = ssum / (float)(cnt > 0 ? cnt : 1);
        }
    }
}

extern "C" void kernel_launch(void* const* d_in, const int* in_sizes, int n_in,
                              void* d_out, int out_size, void* d_ws, size_t ws_size,
                              hipStream_t stream) {
    const float* logits    = (const float*)d_in[0];
    const int*   events    = (const int*)d_in[1];
    const float* durations = (const float*)d_in[2];
    float* out = (float*)d_out;

    char* ws = (char*)d_ws;
    double*         acc     = (double*)ws;
    float2*         psort   = (float2*)(ws + 64);
    int*            lohi    = (int*)(ws + 64 + (size_t)NC * N * sizeof(float2));
    unsigned*       counter = (unsigned*)(ws + 64 + (size_t)NC * N * (sizeof(float2) + sizeof(int)));
    unsigned short* origj   = (unsigned short*)(ws + 64 + (size_t)NC * N * (sizeof(float2) + sizeof(int)) + 64);

    k_prep<<<dim3(1024), 256, 0, stream>>>(logits, durations, events, psort, origj, lohi, acc, counter);
    k_bce<<<dim3(NC * 64), 512, 0, stream>>>(psort, origj, lohi, acc, counter, out);
}

// Round 15
// 87.965 us; speedup vs baseline: 1.0815x; 1.0815x over previous
//
#include <hip/hip_runtime.h>
#include <hip/hip_bf16.h>
#include <math.h>

#define N 2048
#define NC 8

// ws layout:
//   [0, 64)                  : double acc[8]            (zeroed by k_prep block 0)
//   [64, 64+128K)            : float2 psort[8][2048]    {s/ln2, A/ln2} in SCORE-SORTED order
//   [64+128K, 64+192K)       : int    lohi[8][2048]     (lo | hi<<16, per ORIGINAL row)
//   [64+192K, +4)            : unsigned counter         (ticket for fused finalize)
//   [64+192K+64, +32K)       : u16    origj[8][2048]    (sorted pos -> original j)

#if __has_builtin(__builtin_amdgcn_exp2f)
__device__ __forceinline__ float fexp2(float x) { return __builtin_amdgcn_exp2f(x); }
#else
__device__ __forceinline__ float fexp2(float x) { return exp2f(x); }
#endif
#if __has_builtin(__builtin_amdgcn_logf)
__device__ __forceinline__ float flog2(float x) { return __builtin_amdgcn_logf(x); }
#else
__device__ __forceinline__ float flog2(float x) { return log2f(x); }
#endif

#define INV_LN2 1.4426950408889634f
#define LN2_D   0.6931471805599453
#define CLAMP2  (-144.26950408889634f)   /* -100/ln2 : clamp in log2 domain */

// ---------------- Kernel 1: A-sum + score-rank + counting-rank GT -------------
// R15: identical math to R11-R14; ONLY change is #pragma unroll 2 -> 8 on both
// inner loops so 8 ds_read_b128 batch per basic block (latency exposed once
// per 8 elements instead of once per 2). Op order unchanged -> bitwise equal.
__global__ __launch_bounds__(256) void k_prep(const float* __restrict__ logits,
                                              const float* __restrict__ dur,
                                              const int* __restrict__ ev,
                                              float2* __restrict__ psort,
                                              unsigned short* __restrict__ origj,
                                              int* __restrict__ lohi,
                                              double* __restrict__ acc,
                                              unsigned* __restrict__ counter) {
    __shared__ __align__(16) float s[N];                   // 8 KB   (asum)
    __shared__ double part[256];                           // 2 KB   (asum)
    __shared__ int pri[256];                               // 1 KB   (asum rank)
    __shared__ __align__(16) unsigned long long keys[N];   // 16 KB  (sortgt)
    __shared__ int pr[256], pv[256];                       // 2 KB   (sortgt)

    int b = blockIdx.x;
    int tid = threadIdx.x;

    if (b == 0) {  // zero accumulators + ticket for k_bce (stream-ordered)
        if (tid < 8) acc[tid] = 0.0;
        else if (tid == 8) counter[0] = 0u;
    }

    if (b < 512) {
        // ---- A-sum + rank, 32 j's per block, 8 i-slices of 256 ----
        int col = b >> 6, chunk = b & 63;
        for (int k = 0; k < N / 256; ++k) {
            int i = tid + k * 256;
            s[i] = logits[i * NC + col];
        }
        __syncthreads();
        int jl = tid & 31, slice = tid >> 5;   // 32 j-lanes x 8 slices
        int j = chunk * 32 + jl;
        float sj = s[j];
        const float4* s4 = (const float4*)(s + slice * 256);
        int ib = slice * 256;
        double a0 = 0.0, a1 = 0.0, a2 = 0.0, a3 = 0.0;
        int rk = 0;
        #pragma unroll 8
        for (int i = 0; i < 64; ++i) {
            float4 q = s4[i];
            int i0 = ib + 4 * i;
            a0 += (double)fabsf(sj - q.x);
            a1 += (double)fabsf(sj - q.y);
            a2 += (double)fabsf(sj - q.z);
            a3 += (double)fabsf(sj - q.w);
            rk += ((int)(q.x < sj)) | (((int)(q.x == sj)) & (int)(i0 + 0 < j));
            rk += ((int)(q.y < sj)) | (((int)(q.y == sj)) & (int)(i0 + 1 < j));
            rk += ((int)(q.z < sj)) | (((int)(q.z == sj)) & (int)(i0 + 2 < j));
            rk += ((int)(q.w < sj)) | (((int)(q.w == sj)) & (int)(i0 + 3 < j));
        }
        part[tid] = (a0 + a1) + (a2 + a3);
        pri[tid] = rk;
        __syncthreads();
        if (tid < 32) {
            double v = ((part[tid]       + part[tid + 32])  + (part[tid + 64]  + part[tid + 96])) +
                       ((part[tid + 128] + part[tid + 160]) + (part[tid + 192] + part[tid + 224]));
            int r = ((pri[tid]       + pri[tid + 32])  + (pri[tid + 64]  + pri[tid + 96])) +
                    ((pri[tid + 128] + pri[tid + 160]) + (pri[tid + 192] + pri[tid + 224]));
            psort[col * N + r] = make_float2(sj * INV_LN2, (float)v * INV_LN2);
            origj[col * N + r] = (unsigned short)j;
        }
    } else {
        // ---- counting-rank GT windows (R10 b128 form, unroll 8) ----
        int b2 = b - 512;
        int col = b2 >> 6, chunk = b2 & 63;
        for (int k = 0; k < N / 256; ++k) {
            int i = tid + k * 256;
            unsigned int db = __float_as_uint(dur[i * NC + col]);  // dur in [0,1)
            int e = ev[i * NC + col];
            keys[i] = ((unsigned long long)db << 32) | (unsigned int)((i << 1) | e);
        }
        __syncthreads();
        int jl = tid & 31, slice = tid >> 5;
        int j = chunk * 32 + jl;
        unsigned long long kj = keys[j];
        const ulonglong2* k2 = (const ulonglong2*)(keys + slice * 256);
        int rank = 0, evlt = 0;
        #pragma unroll 8
        for (int i = 0; i < 128; ++i) {
            ulonglong2 kk = k2[i];
            int lt0 = (kk.x < kj) ? 1 : 0;
            rank += lt0;
            evlt += lt0 & (int)(kk.x & 1ull);
            int lt1 = (kk.y < kj) ? 1 : 0;
            rank += lt1;
            evlt += lt1 & (int)(kk.y & 1ull);
        }
        pr[tid] = rank;
        pv[tid] = evlt;
        __syncthreads();
        if (tid < 32) {
            int r = ((pr[tid]       + pr[tid + 32])  + (pr[tid + 64]  + pr[tid + 96])) +
                    ((pr[tid + 128] + pr[tid + 160]) + (pr[tid + 192] + pr[tid + 224]));
            int v = ((pv[tid]       + pv[tid + 32])  + (pv[tid + 64]  + pv[tid + 96])) +
                    ((pv[tid + 128] + pv[tid + 160]) + (pv[tid + 192] + pv[tid + 224]));
            int e = (int)(kj & 1ull);
            int hi = e ? (r + 1) : N;
            lohi[col * N + j] = v | (hi << 16);
        }
    }
}

// ---------------- Kernel 2: softmax+BCE, group-of-8 prefetch ------------------
// R15 EXPERIMENT (vs R13 staged): the __all()/continue branch in every k-iter
// of passes 2/3 splits basic blocks, so the compiler cannot hoist the next
// iteration's ds_read past the branch — each of ~48 loads/wave exposes its
// full ~120cy LDS latency (the only model fitting R14's counters: 41us wall,
// 19% VALUBusy, all pipes idle; 48x210cy L2 x 4 lockstep waves x 2 rounds =
// 38us ~= 41 measured). FIX: branchless group-of-8 register prefetch per pass;
// branchy bodies then run on registers. Exposed latency 16x120 -> 2x120/pass.
// VGPR +~40 (<=128, guarded vs the 132-cliff). Op order unchanged -> bitwise.
__global__ __launch_bounds__(512) void k_bce(const float2* __restrict__ psort,
                                             const unsigned short* __restrict__ origj,
                                             const int* __restrict__ lohi,
                                             double* __restrict__ acc,
                                             unsigned* __restrict__ counter,
                                             float* __restrict__ out) {
    int col = blockIdx.x >> 6;   // 0..7
    int rg  = blockIdx.x & 63;   // 0..63 (32 rows each)
    __shared__ float4 sa4[N / 2];   // 16 KB sorted {s,A} pairs
    __shared__ unsigned sow[N / 2]; // 4 KB  origj pairs (u16x2)
    __shared__ double bsum[8];
    int tid = threadIdx.x;
    int wave = tid >> 6, lane = tid & 63;

    const float4* p4 = (const float4*)(psort + (size_t)col * N);
    const unsigned* g4 = (const unsigned*)(origj + (size_t)col * N);
    #pragma unroll
    for (int k = 0; k < 2; ++k) {
        int i = tid + (k << 9);
        sa4[i] = p4[i];
        sow[i] = g4[i];
    }
    __syncthreads();

    int row0 = (rg << 5) + (wave << 2);   // 4 rows per wave, 8 waves
    float sc0 = (float)(N - 1 - 2 * row0);

    int lh[4];
    #pragma unroll
    for (int c = 0; c < 4; ++c) lh[c] = lohi[col * N + row0 + c];

    // pass 1: max of row 0 (branchless; compiler already batches the reads)
    float m = -INFINITY;
    #pragma unroll
    for (int k = 0; k < 16; ++k) {
        float4 q = sa4[lane + (k << 6)];
        float t0 = fmaf(sc0, q.x, -q.y);
        float t1 = fmaf(sc0, q.z, -q.w);
        m = fmaxf(m, fmaxf(t0, t1));
    }
    #pragma unroll
    for (int off = 32; off > 0; off >>= 1)
        m = fmaxf(m, __shfl_xor(m, off, 64));

    // pass 2: group-of-8 prefetch, then branchy bodies on registers
    float se0 = 0.0f, se1 = 0.0f, se2 = 0.0f, se3 = 0.0f;
    #pragma unroll
    for (int kg = 0; kg < 2; ++kg) {
        float4 qv[8];
        #pragma unroll
        for (int t = 0; t < 8; ++t)
            qv[t] = sa4[lane + (((kg << 3) | t) << 6)];
        #pragma unroll
        for (int t = 0; t < 8; ++t) {
            float4 q = qv[t];
            float tsa = q.x + q.x;
            float xa0 = fmaf(sc0, q.x, -q.y) - m;
            float xa3 = fmaf(-3.0f, tsa, xa0);
            float tsb = q.z + q.z;
            float xb0 = fmaf(sc0, q.z, -q.w) - m;
            float xb3 = fmaf(-3.0f, tsb, xb0);
            float hi = fmaxf(fmaxf(xa0, xa3), fmaxf(xb0, xb3));
            if (__all(hi < -152.0f)) continue;   // all E == +0: no contribution
            float xa1 = xa0 - tsa;
            float xa2 = fmaf(-2.0f, tsa, xa0);
            float xb1 = xb0 - tsb;
            float xb2 = fmaf(-2.0f, tsb, xb0);
            se0 += fexp2(xa0); se1 += fexp2(xa1); se2 += fexp2(xa2); se3 += fexp2(xa3);
            se0 += fexp2(xb0); se1 += fexp2(xb1); se2 += fexp2(xb2); se3 += fexp2(xb3);
        }
    }
    #pragma unroll
    for (int off = 32; off > 0; off >>= 1) {
        se0 += __shfl_xor(se0, off, 64);
        se1 += __shfl_xor(se1, off, 64);
        se2 += __shfl_xor(se2, off, 64);
        se3 += __shfl_xor(se3, off, 64);
    }
    float se[4] = {se0, se1, se2, se3};

    float L2v[4], C2v[4], yv[4], w2c[4];
    unsigned lo[4], wl[4];
    double rbase = 0.0;
    #pragma unroll
    for (int c = 0; c < 4; ++c) {
        float L2 = flog2(se[c]);
        L2v[c] = L2;
        rbase -= 2048.0 * (double)L2;
        C2v[c] = CLAMP2 + L2;
        w2c[c] = C2v[c] - L2v[c];        // deep-tier window value (bitwise)
        lo[c] = (unsigned)(lh[c] & 0xffff);
        wl[c] = (unsigned)((lh[c] >> 16) & 0xffff) - lo[c];
        yv[c] = 1.0f / (float)wl[c];
    }
    float minL2 = fminf(fminf(L2v[0], L2v[1]), fminf(L2v[2], L2v[3]));
    float C2min = fminf(fminf(C2v[0], C2v[1]), fminf(C2v[2], C2v[3]));
    float tdeep = fminf(C2min, minL2 - 27.0f);
    float t2    = minL2 - 27.0f;

    // pass 3: group-of-8 prefetch (q + ow); tiered bodies on registers
    float a1[4] = {0.0f, 0.0f, 0.0f, 0.0f};
    float a2[4] = {0.0f, 0.0f, 0.0f, 0.0f};
    int cntD[4] = {0, 0, 0, 0};
    int nL = 0;
    #pragma unroll
    for (int kg = 0; kg < 2; ++kg) {
        float4 qv[8];
        unsigned owv[8];
        #pragma unroll
        for (int t = 0; t < 8; ++t) {
            int idx = lane + (((kg << 3) | t) << 6);
            qv[t] = sa4[idx];
            owv[t] = sow[idx];
        }
        #pragma unroll
        for (int t = 0; t < 8; ++t) {
            float4 q = qv[t];
            unsigned ow = owv[t];
            int ja = (int)(ow & 0xffffu), jb = (int)(ow >> 16);
            float tsa = q.x + q.x;
            float xa0 = fmaf(sc0, q.x, -q.y) - m;
            float xa3 = fmaf(-3.0f, tsa, xa0);
            float tsb = q.z + q.z;
            float xb0 = fmaf(sc0, q.z, -q.w) - m;
            float xb3 = fmaf(-3.0f, tsb, xb0);
            float hi = fmaxf(fmaxf(xa0, xa3), fmaxf(xb0, xb3));
            if (__all(hi < tdeep)) {
                // mx1 == C2v[c] and mx2 == L2v[c] bitwise: only window COUNTS
                ++nL;
                #pragma unroll
                for (int c = 0; c < 4; ++c) {
                    cntD[c] += (int)((unsigned)(ja - lo[c]) < wl[c]);
                    cntD[c] += (int)((unsigned)(jb - lo[c]) < wl[c]);
                }
            } else if (__all(hi < t2)) {
                // mx2 == L2v[c] bitwise (se-E rounds to se); mx1 needs x
                ++nL;
                {
                    float x = xa0;
                    #pragma unroll
                    for (int c = 0; c < 4; ++c) {
                        float mx1 = fmaxf(x, C2v[c]);
                        float w = ((unsigned)(ja - lo[c]) < wl[c]) ? (mx1 - L2v[c]) : 0.0f;
                        a2[c] += w;
                        x -= tsa;
                    }
                }
                {
                    float x = xb0;
                    #pragma unroll
                    for (int c = 0; c < 4; ++c) {
                        float mx1 = fmaxf(x, C2v[c]);
                        float w = ((unsigned)(jb - lo[c]) < wl[c]) ? (mx1 - L2v[c]) : 0.0f;
                        a2[c] += w;
                        x -= tsb;
                    }
                }
            } else {
                // hot: full direct-E path
                float xav[4], xbv[4];
                xav[0] = xa0; xav[1] = xa0 - tsa;
                xav[2] = fmaf(-2.0f, tsa, xa0); xav[3] = xa3;
                xbv[0] = xb0; xbv[1] = xb0 - tsb;
                xbv[2] = fmaf(-2.0f, tsb, xb0); xbv[3] = xb3;
                float Ea[4], Eb[4];
                #pragma unroll
                for (int c = 0; c < 4; ++c) { Ea[c] = fexp2(xav[c]); Eb[c] = fexp2(xbv[c]); }
                #pragma unroll
                for (int c = 0; c < 4; ++c) {
                    float mx2a = fmaxf(flog2(se[c] - Ea[c]), C2v[c]);
                    a1[c] += mx2a;
                    float mx1a = fmaxf(xav[c], C2v[c]);
                    float wa = ((unsigned)(ja - lo[c]) < wl[c]) ? (mx1a - mx2a) : 0.0f;
                    a2[c] += wa;
                    float mx2b = fmaxf(flog2(se[c] - Eb[c]), C2v[c]);
                    a1[c] += mx2b;
                    float mx1b = fmaxf(xbv[c], C2v[c]);
                    float wb = ((unsigned)(jb - lo[c]) < wl[c]) ? (mx1b - mx2b) : 0.0f;
                    a2[c] += wb;
                }
            }
        }
    }
    // closed-form folds: a1 from deep+mid iters; a2 from deep-tier counts
    float fnL2 = 2.0f * (float)nL;
    #pragma unroll
    for (int c = 0; c < 4; ++c) {
        a1[c] = fmaf(fnL2, L2v[c], a1[c]);
        a2[c] = fmaf((float)cntD[c], w2c[c], a2[c]);
    }
    float r = 0.0f;
    #pragma unroll
    for (int c = 0; c < 4; ++c) r += fmaf(yv[c], a2[c], a1[c]);
    #pragma unroll
    for (int off = 32; off > 0; off >>= 1)
        r += __shfl_xor(r, off, 64);

    if (lane == 0) bsum[wave] = rbase + (double)r;
    __syncthreads();
    if (tid == 0) {
        double tot = ((bsum[0] + bsum[1]) + (bsum[2] + bsum[3])) +
                     ((bsum[4] + bsum[5]) + (bsum[6] + bsum[7]));
        atomicAdd(&acc[col], LN2_D * tot);
        __threadfence();
        unsigned old = atomicAdd(counter, 1u);
        if (old == (unsigned)(NC * 64 - 1)) {  // last of 512 blocks
            __threadfence();
            float ssum = 0.0f;
            int cnt = 0;
            for (int c = 0; c < NC; ++c) {
                double av2 = atomicAdd(&acc[c], 0.0);  // device-scope read
                float lc = (float)(-av2 / ((double)N * (double)N));
                if (lc > 0.0f) { ssum += lc; cnt++; }
            }
            out[0] = ssum / (float)(cnt > 0 ? cnt : 1);
        }
    }
}

extern "C" void kernel_launch(void* const* d_in, const int* in_sizes, int n_in,
                              void* d_out, int out_size, void* d_ws, size_t ws_size,
                              hipStream_t stream) {
    const float* logits    = (const float*)d_in[0];
    const int*   events    = (const int*)d_in[1];
    const float* durations = (const float*)d_in[2];
    float* out = (float*)d_out;

    char* ws = (char*)d_ws;
    double*         acc     = (double*)ws;
    float2*         psort   = (float2*)(ws + 64);
    int*            lohi    = (int*)(ws + 64 + (size_t)NC * N * sizeof(float2));
    unsigned*       counter = (unsigned*)(ws + 64 + (size_t)NC * N * (sizeof(float2) + sizeof(int)));
    unsigned short* origj   = (unsigned short*)(ws + 64 + (size_t)NC * N * (sizeof(float2) + sizeof(int)) + 64);

    k_prep<<<dim3(1024), 256, 0, stream>>>(logits, durations, events, psort, origj, lohi, acc, counter);
    k_bce<<<dim3(NC * 64), 512, 0, stream>>>(psort, origj, lohi, acc, counter, out);
}

// Round 16
// 87.134 us; speedup vs baseline: 1.0918x; 1.0095x over previous
//
#include <hip/hip_runtime.h>
#include <hip/hip_bf16.h>
#include <math.h>

#define N 2048
#define NC 8

// ws layout:
//   [0, 64)                  : double acc[8]            (zeroed by k_prep block 0)
//   [64, 64+128K)            : float2 psort[8][2048]    {s/ln2, A/ln2} in SCORE-SORTED order
//   [64+128K, 64+192K)       : int    lohi[8][2048]     (lo | hi<<16, per ORIGINAL row)
//   [64+192K, +4)            : unsigned counter         (ticket for fused finalize)
//   [64+192K+64, +32K)       : u16    origj[8][2048]    (sorted pos -> original j)

#if __has_builtin(__builtin_amdgcn_exp2f)
__device__ __forceinline__ float fexp2(float x) { return __builtin_amdgcn_exp2f(x); }
#else
__device__ __forceinline__ float fexp2(float x) { return exp2f(x); }
#endif
#if __has_builtin(__builtin_amdgcn_logf)
__device__ __forceinline__ float flog2(float x) { return __builtin_amdgcn_logf(x); }
#else
__device__ __forceinline__ float flog2(float x) { return log2f(x); }
#endif

#define INV_LN2 1.4426950408889634f
#define LN2_D   0.6931471805599453
#define CLAMP2  (-144.26950408889634f)   /* -100/ln2 : clamp in log2 domain */

// ---------------- Kernel 1: A-sum + score-rank + counting-rank GT -------------
// R16: unroll 8 -> 16 on both inner loops (continue R15's validated load-
// batching lever). Op order unchanged -> bitwise equal to R11-R15.
__global__ __launch_bounds__(256) void k_prep(const float* __restrict__ logits,
                                              const float* __restrict__ dur,
                                              const int* __restrict__ ev,
                                              float2* __restrict__ psort,
                                              unsigned short* __restrict__ origj,
                                              int* __restrict__ lohi,
                                              double* __restrict__ acc,
                                              unsigned* __restrict__ counter) {
    __shared__ __align__(16) float s[N];                   // 8 KB   (asum)
    __shared__ double part[256];                           // 2 KB   (asum)
    __shared__ int pri[256];                               // 1 KB   (asum rank)
    __shared__ __align__(16) unsigned long long keys[N];   // 16 KB  (sortgt)
    __shared__ int pr[256], pv[256];                       // 2 KB   (sortgt)

    int b = blockIdx.x;
    int tid = threadIdx.x;

    if (b == 0) {  // zero accumulators + ticket for k_bce (stream-ordered)
        if (tid < 8) acc[tid] = 0.0;
        else if (tid == 8) counter[0] = 0u;
    }

    if (b < 512) {
        // ---- A-sum + rank, 32 j's per block, 8 i-slices of 256 ----
        int col = b >> 6, chunk = b & 63;
        for (int k = 0; k < N / 256; ++k) {
            int i = tid + k * 256;
            s[i] = logits[i * NC + col];
        }
        __syncthreads();
        int jl = tid & 31, slice = tid >> 5;   // 32 j-lanes x 8 slices
        int j = chunk * 32 + jl;
        float sj = s[j];
        const float4* s4 = (const float4*)(s + slice * 256);
        int ib = slice * 256;
        double a0 = 0.0, a1 = 0.0, a2 = 0.0, a3 = 0.0;
        int rk = 0;
        #pragma unroll 16
        for (int i = 0; i < 64; ++i) {
            float4 q = s4[i];
            int i0 = ib + 4 * i;
            a0 += (double)fabsf(sj - q.x);
            a1 += (double)fabsf(sj - q.y);
            a2 += (double)fabsf(sj - q.z);
            a3 += (double)fabsf(sj - q.w);
            rk += ((int)(q.x < sj)) | (((int)(q.x == sj)) & (int)(i0 + 0 < j));
            rk += ((int)(q.y < sj)) | (((int)(q.y == sj)) & (int)(i0 + 1 < j));
            rk += ((int)(q.z < sj)) | (((int)(q.z == sj)) & (int)(i0 + 2 < j));
            rk += ((int)(q.w < sj)) | (((int)(q.w == sj)) & (int)(i0 + 3 < j));
        }
        part[tid] = (a0 + a1) + (a2 + a3);
        pri[tid] = rk;
        __syncthreads();
        if (tid < 32) {
            double v = ((part[tid]       + part[tid + 32])  + (part[tid + 64]  + part[tid + 96])) +
                       ((part[tid + 128] + part[tid + 160]) + (part[tid + 192] + part[tid + 224]));
            int r = ((pri[tid]       + pri[tid + 32])  + (pri[tid + 64]  + pri[tid + 96])) +
                    ((pri[tid + 128] + pri[tid + 160]) + (pri[tid + 192] + pri[tid + 224]));
            psort[col * N + r] = make_float2(sj * INV_LN2, (float)v * INV_LN2);
            origj[col * N + r] = (unsigned short)j;
        }
    } else {
        // ---- counting-rank GT windows (R10 b128 form, unroll 16) ----
        int b2 = b - 512;
        int col = b2 >> 6, chunk = b2 & 63;
        for (int k = 0; k < N / 256; ++k) {
            int i = tid + k * 256;
            unsigned int db = __float_as_uint(dur[i * NC + col]);  // dur in [0,1)
            int e = ev[i * NC + col];
            keys[i] = ((unsigned long long)db << 32) | (unsigned int)((i << 1) | e);
        }
        __syncthreads();
        int jl = tid & 31, slice = tid >> 5;
        int j = chunk * 32 + jl;
        unsigned long long kj = keys[j];
        const ulonglong2* k2 = (const ulonglong2*)(keys + slice * 256);
        int rank = 0, evlt = 0;
        #pragma unroll 16
        for (int i = 0; i < 128; ++i) {
            ulonglong2 kk = k2[i];
            int lt0 = (kk.x < kj) ? 1 : 0;
            rank += lt0;
            evlt += lt0 & (int)(kk.x & 1ull);
            int lt1 = (kk.y < kj) ? 1 : 0;
            rank += lt1;
            evlt += lt1 & (int)(kk.y & 1ull);
        }
        pr[tid] = rank;
        pv[tid] = evlt;
        __syncthreads();
        if (tid < 32) {
            int r = ((pr[tid]       + pr[tid + 32])  + (pr[tid + 64]  + pr[tid + 96])) +
                    ((pr[tid + 128] + pr[tid + 160]) + (pr[tid + 192] + pr[tid + 224]));
            int v = ((pv[tid]       + pv[tid + 32])  + (pv[tid + 64]  + pv[tid + 96])) +
                    ((pv[tid + 128] + pv[tid + 160]) + (pv[tid + 192] + pv[tid + 224]));
            int e = (int)(kj & 1ull);
            int hi = e ? (r + 1) : N;
            lohi[col * N + j] = v | (hi << 16);
        }
    }
}

// ---------------- Kernel 2: softmax+BCE, deeper prefetch ----------------------
// R16 (vs R15's 87.96): pass 2 prefetch group 8 -> 16 (whole pass branchless
// prefetch; exposed LDS latency 2x120 -> 1x120). VGPR audit: pass-2 live set
// ~15 regs + 64 prefetch ~= 95 < 128. Pass 3 KEPT at group-of-8 (live ~35 +
// 48 would flirt with the 128 cliff). Op order unchanged -> bitwise.
__global__ __launch_bounds__(512) void k_bce(const float2* __restrict__ psort,
                                             const unsigned short* __restrict__ origj,
                                             const int* __restrict__ lohi,
                                             double* __restrict__ acc,
                                             unsigned* __restrict__ counter,
                                             float* __restrict__ out) {
    int col = blockIdx.x >> 6;   // 0..7
    int rg  = blockIdx.x & 63;   // 0..63 (32 rows each)
    __shared__ float4 sa4[N / 2];   // 16 KB sorted {s,A} pairs
    __shared__ unsigned sow[N / 2]; // 4 KB  origj pairs (u16x2)
    __shared__ double bsum[8];
    int tid = threadIdx.x;
    int wave = tid >> 6, lane = tid & 63;

    const float4* p4 = (const float4*)(psort + (size_t)col * N);
    const unsigned* g4 = (const unsigned*)(origj + (size_t)col * N);
    #pragma unroll
    for (int k = 0; k < 2; ++k) {
        int i = tid + (k << 9);
        sa4[i] = p4[i];
        sow[i] = g4[i];
    }
    __syncthreads();

    int row0 = (rg << 5) + (wave << 2);   // 4 rows per wave, 8 waves
    float sc0 = (float)(N - 1 - 2 * row0);

    int lh[4];
    #pragma unroll
    for (int c = 0; c < 4; ++c) lh[c] = lohi[col * N + row0 + c];

    // pass 1: max of row 0 (branchless)
    float m = -INFINITY;
    #pragma unroll
    for (int k = 0; k < 16; ++k) {
        float4 q = sa4[lane + (k << 6)];
        float t0 = fmaf(sc0, q.x, -q.y);
        float t1 = fmaf(sc0, q.z, -q.w);
        m = fmaxf(m, fmaxf(t0, t1));
    }
    #pragma unroll
    for (int off = 32; off > 0; off >>= 1)
        m = fmaxf(m, __shfl_xor(m, off, 64));

    // pass 2: single group-of-16 prefetch, then branchy bodies on registers
    float se0 = 0.0f, se1 = 0.0f, se2 = 0.0f, se3 = 0.0f;
    {
        float4 qv[16];
        #pragma unroll
        for (int t = 0; t < 16; ++t)
            qv[t] = sa4[lane + (t << 6)];
        #pragma unroll
        for (int t = 0; t < 16; ++t) {
            float4 q = qv[t];
            float tsa = q.x + q.x;
            float xa0 = fmaf(sc0, q.x, -q.y) - m;
            float xa3 = fmaf(-3.0f, tsa, xa0);
            float tsb = q.z + q.z;
            float xb0 = fmaf(sc0, q.z, -q.w) - m;
            float xb3 = fmaf(-3.0f, tsb, xb0);
            float hi = fmaxf(fmaxf(xa0, xa3), fmaxf(xb0, xb3));
            if (__all(hi < -152.0f)) continue;   // all E == +0: no contribution
            float xa1 = xa0 - tsa;
            float xa2 = fmaf(-2.0f, tsa, xa0);
            float xb1 = xb0 - tsb;
            float xb2 = fmaf(-2.0f, tsb, xb0);
            se0 += fexp2(xa0); se1 += fexp2(xa1); se2 += fexp2(xa2); se3 += fexp2(xa3);
            se0 += fexp2(xb0); se1 += fexp2(xb1); se2 += fexp2(xb2); se3 += fexp2(xb3);
        }
    }
    #pragma unroll
    for (int off = 32; off > 0; off >>= 1) {
        se0 += __shfl_xor(se0, off, 64);
        se1 += __shfl_xor(se1, off, 64);
        se2 += __shfl_xor(se2, off, 64);
        se3 += __shfl_xor(se3, off, 64);
    }
    float se[4] = {se0, se1, se2, se3};

    float L2v[4], C2v[4], yv[4], w2c[4];
    unsigned lo[4], wl[4];
    double rbase = 0.0;
    #pragma unroll
    for (int c = 0; c < 4; ++c) {
        float L2 = flog2(se[c]);
        L2v[c] = L2;
        rbase -= 2048.0 * (double)L2;
        C2v[c] = CLAMP2 + L2;
        w2c[c] = C2v[c] - L2v[c];        // deep-tier window value (bitwise)
        lo[c] = (unsigned)(lh[c] & 0xffff);
        wl[c] = (unsigned)((lh[c] >> 16) & 0xffff) - lo[c];
        yv[c] = 1.0f / (float)wl[c];
    }
    float minL2 = fminf(fminf(L2v[0], L2v[1]), fminf(L2v[2], L2v[3]));
    float C2min = fminf(fminf(C2v[0], C2v[1]), fminf(C2v[2], C2v[3]));
    float tdeep = fminf(C2min, minL2 - 27.0f);
    float t2    = minL2 - 27.0f;

    // pass 3: group-of-8 prefetch (q + ow); tiered bodies on registers
    float a1[4] = {0.0f, 0.0f, 0.0f, 0.0f};
    float a2[4] = {0.0f, 0.0f, 0.0f, 0.0f};
    int cntD[4] = {0, 0, 0, 0};
    int nL = 0;
    #pragma unroll
    for (int kg = 0; kg < 2; ++kg) {
        float4 qv[8];
        unsigned owv[8];
        #pragma unroll
        for (int t = 0; t < 8; ++t) {
            int idx = lane + (((kg << 3) | t) << 6);
            qv[t] = sa4[idx];
            owv[t] = sow[idx];
        }
        #pragma unroll
        for (int t = 0; t < 8; ++t) {
            float4 q = qv[t];
            unsigned ow = owv[t];
            int ja = (int)(ow & 0xffffu), jb = (int)(ow >> 16);
            float tsa = q.x + q.x;
            float xa0 = fmaf(sc0, q.x, -q.y) - m;
            float xa3 = fmaf(-3.0f, tsa, xa0);
            float tsb = q.z + q.z;
            float xb0 = fmaf(sc0, q.z, -q.w) - m;
            float xb3 = fmaf(-3.0f, tsb, xb0);
            float hi = fmaxf(fmaxf(xa0, xa3), fmaxf(xb0, xb3));
            if (__all(hi < tdeep)) {
                // mx1 == C2v[c] and mx2 == L2v[c] bitwise: only window COUNTS
                ++nL;
                #pragma unroll
                for (int c = 0; c < 4; ++c) {
                    cntD[c] += (int)((unsigned)(ja - lo[c]) < wl[c]);
                    cntD[c] += (int)((unsigned)(jb - lo[c]) < wl[c]);
                }
            } else if (__all(hi < t2)) {
                // mx2 == L2v[c] bitwise (se-E rounds to se); mx1 needs x
                ++nL;
                {
                    float x = xa0;
                    #pragma unroll
                    for (int c = 0; c < 4; ++c) {
                        float mx1 = fmaxf(x, C2v[c]);
                        float w = ((unsigned)(ja - lo[c]) < wl[c]) ? (mx1 - L2v[c]) : 0.0f;
                        a2[c] += w;
                        x -= tsa;
                    }
                }
                {
                    float x = xb0;
                    #pragma unroll
                    for (int c = 0; c < 4; ++c) {
                        float mx1 = fmaxf(x, C2v[c]);
                        float w = ((unsigned)(jb - lo[c]) < wl[c]) ? (mx1 - L2v[c]) : 0.0f;
                        a2[c] += w;
                        x -= tsb;
                    }
                }
            } else {
                // hot: full direct-E path
                float xav[4], xbv[4];
                xav[0] = xa0; xav[1] = xa0 - tsa;
                xav[2] = fmaf(-2.0f, tsa, xa0); xav[3] = xa3;
                xbv[0] = xb0; xbv[1] = xb0 - tsb;
                xbv[2] = fmaf(-2.0f, tsb, xb0); xbv[3] = xb3;
                float Ea[4], Eb[4];
                #pragma unroll
                for (int c = 0; c < 4; ++c) { Ea[c] = fexp2(xav[c]); Eb[c] = fexp2(xbv[c]); }
                #pragma unroll
                for (int c = 0; c < 4; ++c) {
                    float mx2a = fmaxf(flog2(se[c] - Ea[c]), C2v[c]);
                    a1[c] += mx2a;
                    float mx1a = fmaxf(xav[c], C2v[c]);
                    float wa = ((unsigned)(ja - lo[c]) < wl[c]) ? (mx1a - mx2a) : 0.0f;
                    a2[c] += wa;
                    float mx2b = fmaxf(flog2(se[c] - Eb[c]), C2v[c]);
                    a1[c] += mx2b;
                    float mx1b = fmaxf(xbv[c], C2v[c]);
                    float wb = ((unsigned)(jb - lo[c]) < wl[c]) ? (mx1b - mx2b) : 0.0f;
                    a2[c] += wb;
                }
            }
        }
    }
    // closed-form folds: a1 from deep+mid iters; a2 from deep-tier counts
    float fnL2 = 2.0f * (float)nL;
    #pragma unroll
    for (int c = 0; c < 4; ++c) {
        a1[c] = fmaf(fnL2, L2v[c], a1[c]);
        a2[c] = fmaf((float)cntD[c], w2c[c], a2[c]);
    }
    float r = 0.0f;
    #pragma unroll
    for (int c = 0; c < 4; ++c) r += fmaf(yv[c], a2[c], a1[c]);
    #pragma unroll
    for (int off = 32; off > 0; off >>= 1)
        r += __shfl_xor(r, off, 64);

    if (lane == 0) bsum[wave] = rbase + (double)r;
    __syncthreads();
    if (tid == 0) {
        double tot = ((bsum[0] + bsum[1]) + (bsum[2] + bsum[3])) +
                     ((bsum[4] + bsum[5]) + (bsum[6] + bsum[7]));
        atomicAdd(&acc[col], LN2_D * tot);
        __threadfence();
        unsigned old = atomicAdd(counter, 1u);
        if (old == (unsigned)(NC * 64 - 1)) {  // last of 512 blocks
            __threadfence();
            float ssum = 0.0f;
            int cnt = 0;
            for (int c = 0; c < NC; ++c) {
                double av2 = atomicAdd(&acc[c], 0.0);  // device-scope read
                float lc = (float)(-av2 / ((double)N * (double)N));
                if (lc > 0.0f) { ssum += lc; cnt++; }
            }
            out[0] = ssum / (float)(cnt > 0 ? cnt : 1);
        }
    }
}

extern "C" void kernel_launch(void* const* d_in, const int* in_sizes, int n_in,
                              void* d_out, int out_size, void* d_ws, size_t ws_size,
                              hipStream_t stream) {
    const float* logits    = (const float*)d_in[0];
    const int*   events    = (const int*)d_in[1];
    const float* durations = (const float*)d_in[2];
    float* out = (float*)d_out;

    char* ws = (char*)d_ws;
    double*         acc     = (double*)ws;
    float2*         psort   = (float2*)(ws + 64);
    int*            lohi    = (int*)(ws + 64 + (size_t)NC * N * sizeof(float2));
    unsigned*       counter = (unsigned*)(ws + 64 + (size_t)NC * N * (sizeof(float2) + sizeof(int)));
    unsigned short* origj   = (unsigned short*)(ws + 64 + (size_t)NC * N * (sizeof(float2) + sizeof(int)) + 64);

    k_prep<<<dim3(1024), 256, 0, stream>>>(logits, durations, events, psort, origj, lohi, acc, counter);
    k_bce<<<dim3(NC * 64), 512, 0, stream>>>(psort, origj, lohi, acc, counter, out);
}